// Round 1
// baseline (126482.251 us; speedup 1.0000x reference)
//
#include <hip/hip_runtime.h>
#include <cstdint>

// Problem constants
static constexpr int BATCH  = 32;
static constexpr int TLEN   = 2048;
static constexpr int DIN    = 256;    // input dim
static constexpr int HDIM   = 512;    // hidden dim
static constexpr int G4     = 2048;   // 4*HDIM (gate cols, order i,f,g,o)
static constexpr int KTOT   = 768;    // DIN + HDIM fused reduction
static constexpr int NSLICE = 8;      // blocks per batch
static constexpr int HCB    = 64;     // h-cols per block
static constexpr int CPB    = 256;    // gate-cols per block (4 * HCB)
static constexpr int NTHR   = 512;    // 8 waves
static constexpr int NWAVE  = 8;
static constexpr int KL     = 96;     // k-values per wave
static constexpr int KL2    = 48;     // packed f16x2 (u32) per wave
static constexpr int NBLK   = BATCH * NSLICE;  // 256 blocks = 1/CU

typedef _Float16 h2v __attribute__((ext_vector_type(2)));

__device__ __forceinline__ uint32_t pack_f16x2(float a, float b) {
    h2v v;
    v[0] = (_Float16)a;   // scalar f32->f16 converts RTN
    v[1] = (_Float16)b;
    return __builtin_bit_cast(uint32_t, v);
}

__device__ __forceinline__ float dot2f(uint32_t w, uint32_t u, float acc) {
#if __has_builtin(__builtin_amdgcn_fdot2)
    return __builtin_amdgcn_fdot2(__builtin_bit_cast(h2v, w),
                                  __builtin_bit_cast(h2v, u), acc, false);
#else
    h2v a = __builtin_bit_cast(h2v, w);
    h2v b = __builtin_bit_cast(h2v, u);
    return acc + (float)a[0] * (float)b[0] + (float)a[1] * (float)b[1];
#endif
}

__device__ __forceinline__ float sigmoidf_(float x) {
    return 1.0f / (1.0f + __expf(-x));
}
// tanh via exp; handles +-inf saturation correctly
__device__ __forceinline__ float tanhf_(float x) {
    return 1.0f - 2.0f / (1.0f + __expf(2.0f * x));
}

// Persistent LSTM: one launch runs all 2048 timesteps.
// grid = 32 batches x 8 slices, block = 512 threads, 1 block/CU.
// Per-batch sync domain: 8 slices exchange h through a global f16 double
// buffer guarded by per-slice monotonic step flags (acquire/release, agent).
__global__ __launch_bounds__(NTHR, 2) void lstm_persist(
    const float* __restrict__ x, const int* __restrict__ lens,
    const float* __restrict__ Wi, const float* __restrict__ Wh,
    const float* __restrict__ bias, float* __restrict__ out,
    uint32_t* __restrict__ flags, uint16_t* __restrict__ hbuf)
{
    // Block -> (batch, slice); keeps a batch's 8 blocks on one XCD under the
    // blockIdx%8 round-robin heuristic (perf only, not correctness).
    const int bid = blockIdx.x;
    const int xcd = bid & 7;
    const int t8  = bid >> 3;          // 0..31
    const int b   = xcd * 4 + (t8 & 3);
    const int s   = t8 >> 2;           // slice 0..7

    const int tid = threadIdx.x;
    const int w   = tid >> 6;          // wave 0..7 -> k-chunk [96w, 96w+96)
    const int l   = tid & 63;          // lane -> gate-cols {4l..4l+3}

    __shared__ __align__(16) uint32_t u_lds[KTOT / 2];  // [x(128) | h(256)] f16x2
    __shared__ float gp[NWAVE][CPB];                    // per-wave partial gates

    // ---- one-time: weight slice -> registers, packed f16x2 --------------
    // wgt[q][m] covers gate-col (4l+q), k = {96w+2m, 96w+2m+1};
    // k<256 indexes Wi rows, k>=256 indexes Wh rows (fused operand order).
    uint32_t wgt[4][KL2];
    #pragma unroll
    for (int q = 0; q < 4; ++q) {
        const int c    = 4 * l + q;                       // local gate-col
        const int gcol = (c >> 6) * HDIM + s * HCB + (c & 63);
        #pragma unroll
        for (int m = 0; m < KL2; ++m) {
            const int k0 = KL * w + 2 * m;
            const int k1 = k0 + 1;
            const float f0 = (k0 < DIN) ? Wi[(size_t)k0 * G4 + gcol]
                                        : Wh[(size_t)(k0 - DIN) * G4 + gcol];
            const float f1 = (k1 < DIN) ? Wi[(size_t)k1 * G4 + gcol]
                                        : Wh[(size_t)(k1 - DIN) * G4 + gcol];
            wgt[q][m] = pack_f16x2(f0, f1);
        }
    }

    // update-thread persistent state (wave 0, lane j owns h-col s*64+j)
    float c_st = 0.f, lc_st = 0.f, lh_st = 0.f;
    float b_i = 0.f, b_f = 0.f, b_g = 0.f, b_o = 0.f;
    if (tid < HCB) {
        const int col = s * HCB + tid;
        b_i = bias[col];
        b_f = bias[HDIM + col];
        b_g = bias[2 * HDIM + col];
        b_o = bias[3 * HDIM + col];
    }
    const int len_b = lens[b];

    uint32_t* flg = flags + b * NSLICE;
    const float* xb = x + (size_t)b * TLEN * DIN;
    float* ys = out + 2 * BATCH * HDIM;   // out = [lc | lh | ys]

    for (int t = 0; t < TLEN; ++t) {
        // stage x_t (h-independent -> before the wait)
        if (tid < DIN / 2) {
            const float2 xx = ((const float2*)(xb + (size_t)t * DIN))[tid];
            u_lds[tid] = pack_f16x2(xx.x, xx.y);
        }
        // wait until every slice of this batch published h_t.
        // flag[g] = #steps completed by slice g; min-based wait makes the
        // 2-deep h double-buffer race-free.
        {
            const uint32_t target = (uint32_t)t;
            for (;;) {
                uint32_t v = target;
                if (l < NSLICE)
                    v = __hip_atomic_load(&flg[l], __ATOMIC_ACQUIRE,
                                          __HIP_MEMORY_SCOPE_AGENT);
                if (__all(v >= target)) break;
            }
        }
        // stage h_t from global double buffer (parity t&1)
        const uint32_t* hsrc =
            (const uint32_t*)(hbuf + ((size_t)(t & 1) * BATCH + b) * HDIM);
        if (tid >= 128 && tid < 128 + HDIM / 2) u_lds[tid] = hsrc[tid - 128];
        __syncthreads();

        // dot phase: 4 gate-cols per lane, wave's 96-k chunk, fp32 acc
        float a0 = 0.f, a1 = 0.f, a2 = 0.f, a3 = 0.f;
        const uint4* uv = (const uint4*)u_lds + w * (KL2 / 4);
        #pragma unroll
        for (int m4 = 0; m4 < KL2 / 4; ++m4) {
            const uint4 uu = uv[m4];   // broadcast ds_read_b128
            a0 = dot2f(wgt[0][4 * m4 + 0], uu.x, a0);
            a0 = dot2f(wgt[0][4 * m4 + 1], uu.y, a0);
            a0 = dot2f(wgt[0][4 * m4 + 2], uu.z, a0);
            a0 = dot2f(wgt[0][4 * m4 + 3], uu.w, a0);
            a1 = dot2f(wgt[1][4 * m4 + 0], uu.x, a1);
            a1 = dot2f(wgt[1][4 * m4 + 1], uu.y, a1);
            a1 = dot2f(wgt[1][4 * m4 + 2], uu.z, a1);
            a1 = dot2f(wgt[1][4 * m4 + 3], uu.w, a1);
            a2 = dot2f(wgt[2][4 * m4 + 0], uu.x, a2);
            a2 = dot2f(wgt[2][4 * m4 + 1], uu.y, a2);
            a2 = dot2f(wgt[2][4 * m4 + 2], uu.z, a2);
            a2 = dot2f(wgt[2][4 * m4 + 3], uu.w, a2);
            a3 = dot2f(wgt[3][4 * m4 + 0], uu.x, a3);
            a3 = dot2f(wgt[3][4 * m4 + 1], uu.y, a3);
            a3 = dot2f(wgt[3][4 * m4 + 2], uu.z, a3);
            a3 = dot2f(wgt[3][4 * m4 + 3], uu.w, a3);
        }
        float4 av;
        av.x = a0; av.y = a1; av.z = a2; av.w = a3;
        *(float4*)&gp[w][4 * l] = av;
        __syncthreads();

        // update phase: wave 0 reduces 8 k-chunks, applies gates
        if (tid < HCB) {
            float si = b_i, sf = b_f, sg = b_g, so = b_o;
            #pragma unroll
            for (int ww = 0; ww < NWAVE; ++ww) {
                si += gp[ww][tid];
                sf += gp[ww][HCB + tid];
                sg += gp[ww][2 * HCB + tid];
                so += gp[ww][3 * HCB + tid];
            }
            const float ig = sigmoidf_(si);
            const float fg = sigmoidf_(sf);
            const float gg = tanhf_(sg);
            const float og = sigmoidf_(so);
            const float cn = fg * c_st + ig * gg;
            const float hn = og * tanhf_(cn);
            c_st = cn;
            if (t < len_b) { lc_st = cn; lh_st = hn; }
            // publish f16 h_{t+1} to the other parity buffer
            uint16_t* hdst = hbuf +
                ((size_t)((t + 1) & 1) * BATCH + b) * HDIM + s * HCB;
            const _Float16 hf = (_Float16)hn;
            hdst[tid] = __builtin_bit_cast(uint16_t, hf);
            // ys output (fp32, unmasked like the reference scan)
            ys[((size_t)b * TLEN + t) * HDIM + s * HCB + tid] = hn;
        }
        __threadfence();
        if (tid == 0)
            __hip_atomic_store(&flg[s], (uint32_t)(t + 1), __ATOMIC_RELEASE,
                               __HIP_MEMORY_SCOPE_AGENT);
    }

    // latched carry outputs
    if (tid < HCB) {
        out[(size_t)b * HDIM + s * HCB + tid] = lc_st;
        out[BATCH * HDIM + (size_t)b * HDIM + s * HCB + tid] = lh_st;
    }
}

extern "C" void kernel_launch(void* const* d_in, const int* in_sizes, int n_in,
                              void* d_out, int out_size, void* d_ws, size_t ws_size,
                              hipStream_t stream)
{
    const float* x    = (const float*)d_in[0];   // [32,2048,256] f32
    const int*   lens = (const int*)d_in[1];     // [32] i32
    const float* Wi   = (const float*)d_in[2];   // [256,2048] f32
    const float* Wh   = (const float*)d_in[3];   // [512,2048] f32
    const float* bias = (const float*)d_in[4];   // [2048] f32
    float* out = (float*)d_out;                  // [lc(16384) | lh(16384) | ys]

    uint32_t* flags = (uint32_t*)d_ws;                       // 256 * u32
    uint16_t* hbuf  = (uint16_t*)((char*)d_ws + 1024);       // [2][32][512] f16
    const size_t init_bytes = 1024 + (size_t)2 * BATCH * HDIM * sizeof(uint16_t);
    // flags must start at 0 and h parity-0 buffer must be zero (h_0 = 0);
    // d_ws is re-poisoned to 0xAA before every timed launch.
    hipMemsetAsync(d_ws, 0, init_bytes, stream);

    hipLaunchKernelGGL(lstm_persist, dim3(NBLK), dim3(NTHR), 0, stream,
                       x, lens, Wi, Wh, bias, out, flags, hbuf);
}

// Round 2
// 6992.216 us; speedup vs baseline: 18.0890x; 18.0890x over previous
//
#include <hip/hip_runtime.h>
#include <cstdint>

// Problem constants
static constexpr int BATCH  = 32;
static constexpr int TLEN   = 2048;
static constexpr int DIN    = 256;    // input dim
static constexpr int HDIM   = 512;    // hidden dim
static constexpr int G4     = 2048;   // 4*HDIM (gate cols, order i,f,g,o)
static constexpr int KTOT   = 768;    // DIN + HDIM fused reduction
static constexpr int NSLICE = 8;      // blocks per batch
static constexpr int HCB    = 64;     // h-cols per block
static constexpr int CPB    = 256;    // gate-cols per block (4 * HCB)
static constexpr int NTHR   = 512;    // 8 waves
static constexpr int NWAVE  = 8;
static constexpr int KL     = 96;     // k-values per wave
static constexpr int KL2    = 48;     // packed f16x2 (u32) per wave
static constexpr int NBLK   = BATCH * NSLICE;  // 256 blocks = 1/CU
static constexpr int FLAG_STRIDE = 32;         // u32 per batch: 128B line, no false sharing

typedef _Float16 h2v __attribute__((ext_vector_type(2)));

__device__ __forceinline__ uint32_t pack_f16x2(float a, float b) {
    h2v v;
    v[0] = (_Float16)a;   // scalar f32->f16 converts RTN
    v[1] = (_Float16)b;
    return __builtin_bit_cast(uint32_t, v);
}

__device__ __forceinline__ float dot2f(uint32_t w, uint32_t u, float acc) {
#if __has_builtin(__builtin_amdgcn_fdot2)
    return __builtin_amdgcn_fdot2(__builtin_bit_cast(h2v, w),
                                  __builtin_bit_cast(h2v, u), acc, false);
#else
    h2v a = __builtin_bit_cast(h2v, w);
    h2v b = __builtin_bit_cast(h2v, u);
    return acc + (float)a[0] * (float)b[0] + (float)a[1] * (float)b[1];
#endif
}

__device__ __forceinline__ float sigmoidf_(float x) {
    return 1.0f / (1.0f + __expf(-x));
}
// tanh via exp; handles +-inf saturation correctly
__device__ __forceinline__ float tanhf_(float x) {
    return 1.0f - 2.0f / (1.0f + __expf(2.0f * x));
}

// Persistent LSTM: one launch runs all 2048 timesteps.
// grid = 32 batches x 8 slices, block = 512 threads, 1 block/CU.
//
// Cross-block h exchange: RELAXED agent-scope atomics ONLY. On gfx950 the
// per-XCD L2s are non-coherent; acquire/release/fence at agent scope lower
// to L2 writeback/invalidate ops. R1 post-mortem: 8 waves/block spinning on
// ACQUIRE loads + all-thread __threadfence per step = cache-maintenance storm
// = 61us/step with VALUBusy 1.2%. Relaxed agent atomics bypass the
// non-coherent caches per-op (coherence point = fabric/MALL) with no
// invalidates; ordering is done manually:
//   writer: h stores (relaxed agent) -> s_waitcnt vmcnt(0) -> flag store
//   reader: poll flag (relaxed agent) -> compiler barrier -> h loads
__global__ __launch_bounds__(NTHR, 2) void lstm_persist(
    const float* __restrict__ x, const int* __restrict__ lens,
    const float* __restrict__ Wi, const float* __restrict__ Wh,
    const float* __restrict__ bias, float* __restrict__ out,
    uint32_t* __restrict__ flags, uint16_t* __restrict__ hbuf)
{
    // Block -> (batch, slice); keeps a batch's 8 blocks on one XCD under the
    // blockIdx%8 round-robin heuristic (perf only, not correctness).
    const int bid = blockIdx.x;
    const int xcd = bid & 7;
    const int t8  = bid >> 3;          // 0..31
    const int b   = xcd * 4 + (t8 & 3);
    const int s   = t8 >> 2;           // slice 0..7

    const int tid = threadIdx.x;
    const int w   = tid >> 6;          // wave 0..7 -> k-chunk [96w, 96w+96)
    const int l   = tid & 63;          // lane -> gate-cols {4l..4l+3}

    __shared__ __align__(16) uint32_t u_lds[KTOT / 2];  // [x(128) | h(256)] f16x2
    __shared__ float gp[NWAVE][CPB];                    // per-wave partial gates

    // ---- one-time: weight slice -> registers, packed f16x2 --------------
    // wgt[q][m] covers gate-col (4l+q), k = {96w+2m, 96w+2m+1};
    // k<256 indexes Wi rows, k>=256 indexes Wh rows (fused operand order).
    uint32_t wgt[4][KL2];
    #pragma unroll
    for (int q = 0; q < 4; ++q) {
        const int c    = 4 * l + q;                       // local gate-col
        const int gcol = (c >> 6) * HDIM + s * HCB + (c & 63);
        #pragma unroll
        for (int m = 0; m < KL2; ++m) {
            const int k0 = KL * w + 2 * m;
            const int k1 = k0 + 1;
            const float f0 = (k0 < DIN) ? Wi[(size_t)k0 * G4 + gcol]
                                        : Wh[(size_t)(k0 - DIN) * G4 + gcol];
            const float f1 = (k1 < DIN) ? Wi[(size_t)k1 * G4 + gcol]
                                        : Wh[(size_t)(k1 - DIN) * G4 + gcol];
            wgt[q][m] = pack_f16x2(f0, f1);
        }
    }

    // update-thread persistent state (wave 0, lane j owns h-col s*64+j)
    float c_st = 0.f, lc_st = 0.f, lh_st = 0.f;
    float b_i = 0.f, b_f = 0.f, b_g = 0.f, b_o = 0.f;
    if (tid < HCB) {
        const int col = s * HCB + tid;
        b_i = bias[col];
        b_f = bias[HDIM + col];
        b_g = bias[2 * HDIM + col];
        b_o = bias[3 * HDIM + col];
    }
    const int len_b = lens[b];

    uint32_t* flg = flags + b * FLAG_STRIDE;
    const float* xb = x + (size_t)b * TLEN * DIN;
    float* ys = out + 2 * BATCH * HDIM;   // out = [lc | lh | ys]

    for (int t = 0; t < TLEN; ++t) {
        if (w == 0) {
            // wave 0: poll until every slice of this batch published h_t,
            // then stage h_t -> LDS. flag[g] = #steps completed by slice g;
            // min-based wait makes the 2-deep h double-buffer race-free.
            const uint32_t target = (uint32_t)t;
            for (;;) {
                uint32_t v = target;
                if (l < NSLICE)
                    v = __hip_atomic_load(&flg[l], __ATOMIC_RELAXED,
                                          __HIP_MEMORY_SCOPE_AGENT);
                if (__all(v >= target)) break;
            }
            asm volatile("" ::: "memory");  // keep h loads after poll exit
            const uint32_t* hsrc =
                (const uint32_t*)(hbuf + ((size_t)(t & 1) * BATCH + b) * HDIM);
            #pragma unroll
            for (int q = 0; q < 4; ++q) {
                const uint32_t hv = __hip_atomic_load(
                    &hsrc[64 * q + l], __ATOMIC_RELAXED,
                    __HIP_MEMORY_SCOPE_AGENT);
                u_lds[128 + 64 * q + l] = hv;
            }
        } else if (tid >= 256 && tid < 256 + DIN / 2) {
            // waves 4-5: stage x_t (h-independent)
            const int i = tid - 256;
            const float2 xx = ((const float2*)(xb + (size_t)t * DIN))[i];
            u_lds[i] = pack_f16x2(xx.x, xx.y);
        }
        __syncthreads();

        // dot phase: 4 gate-cols per lane, wave's 96-k chunk, fp32 acc
        float a0 = 0.f, a1 = 0.f, a2 = 0.f, a3 = 0.f;
        const uint4* uv = (const uint4*)u_lds + w * (KL2 / 4);
        #pragma unroll
        for (int m4 = 0; m4 < KL2 / 4; ++m4) {
            const uint4 uu = uv[m4];   // broadcast ds_read_b128
            a0 = dot2f(wgt[0][4 * m4 + 0], uu.x, a0);
            a0 = dot2f(wgt[0][4 * m4 + 1], uu.y, a0);
            a0 = dot2f(wgt[0][4 * m4 + 2], uu.z, a0);
            a0 = dot2f(wgt[0][4 * m4 + 3], uu.w, a0);
            a1 = dot2f(wgt[1][4 * m4 + 0], uu.x, a1);
            a1 = dot2f(wgt[1][4 * m4 + 1], uu.y, a1);
            a1 = dot2f(wgt[1][4 * m4 + 2], uu.z, a1);
            a1 = dot2f(wgt[1][4 * m4 + 3], uu.w, a1);
            a2 = dot2f(wgt[2][4 * m4 + 0], uu.x, a2);
            a2 = dot2f(wgt[2][4 * m4 + 1], uu.y, a2);
            a2 = dot2f(wgt[2][4 * m4 + 2], uu.z, a2);
            a2 = dot2f(wgt[2][4 * m4 + 3], uu.w, a2);
            a3 = dot2f(wgt[3][4 * m4 + 0], uu.x, a3);
            a3 = dot2f(wgt[3][4 * m4 + 1], uu.y, a3);
            a3 = dot2f(wgt[3][4 * m4 + 2], uu.z, a3);
            a3 = dot2f(wgt[3][4 * m4 + 3], uu.w, a3);
        }
        float4 av;
        av.x = a0; av.y = a1; av.z = a2; av.w = a3;
        *(float4*)&gp[w][4 * l] = av;
        __syncthreads();

        // update phase: wave 0 reduces 8 k-chunks, applies gates
        if (tid < HCB) {
            float si = b_i, sf = b_f, sg = b_g, so = b_o;
            #pragma unroll
            for (int ww = 0; ww < NWAVE; ++ww) {
                si += gp[ww][tid];
                sf += gp[ww][HCB + tid];
                sg += gp[ww][2 * HCB + tid];
                so += gp[ww][3 * HCB + tid];
            }
            const float ig = sigmoidf_(si);
            const float fg = sigmoidf_(sf);
            const float gg = tanhf_(sg);
            const float og = sigmoidf_(so);
            const float cn = fg * c_st + ig * gg;
            const float hn = og * tanhf_(cn);
            c_st = cn;
            if (t < len_b) { lc_st = cn; lh_st = hn; }
            // publish f16 h_{t+1} to the other parity buffer (relaxed agent:
            // bypasses non-coherent L1/L2, lands at the coherence point)
            uint16_t* hdst = hbuf +
                ((size_t)((t + 1) & 1) * BATCH + b) * HDIM + s * HCB;
            const _Float16 hf = (_Float16)hn;
            __hip_atomic_store(&hdst[tid], __builtin_bit_cast(uint16_t, hf),
                               __ATOMIC_RELAXED, __HIP_MEMORY_SCOPE_AGENT);
            // ys output (fp32, unmasked like the reference scan)
            ys[((size_t)b * TLEN + t) * HDIM + s * HCB + tid] = hn;
        }
        if (tid == 0) {
            // vmcnt is per-wave: this waits for ALL of wave 0's h stores,
            // then publishes the step flag. No cache-maintenance ops.
            asm volatile("s_waitcnt vmcnt(0)" ::: "memory");
            __hip_atomic_store(&flg[s], (uint32_t)(t + 1), __ATOMIC_RELAXED,
                               __HIP_MEMORY_SCOPE_AGENT);
        }
    }

    // latched carry outputs
    if (tid < HCB) {
        out[(size_t)b * HDIM + s * HCB + tid] = lc_st;
        out[BATCH * HDIM + (size_t)b * HDIM + s * HCB + tid] = lh_st;
    }
}

extern "C" void kernel_launch(void* const* d_in, const int* in_sizes, int n_in,
                              void* d_out, int out_size, void* d_ws, size_t ws_size,
                              hipStream_t stream)
{
    const float* x    = (const float*)d_in[0];   // [32,2048,256] f32
    const int*   lens = (const int*)d_in[1];     // [32] i32
    const float* Wi   = (const float*)d_in[2];   // [256,2048] f32
    const float* Wh   = (const float*)d_in[3];   // [512,2048] f32
    const float* bias = (const float*)d_in[4];   // [2048] f32
    float* out = (float*)d_out;                  // [lc(16384) | lh(16384) | ys]

    uint32_t* flags = (uint32_t*)d_ws;           // [32][32] u32 (128B/batch)
    const size_t flag_bytes = (size_t)BATCH * FLAG_STRIDE * sizeof(uint32_t);
    uint16_t* hbuf  = (uint16_t*)((char*)d_ws + flag_bytes);  // [2][32][512] f16
    const size_t init_bytes = flag_bytes + (size_t)2 * BATCH * HDIM * sizeof(uint16_t);
    // flags must start at 0 and h parity-0 buffer must be zero (h_0 = 0);
    // d_ws is re-poisoned to 0xAA before every timed launch.
    hipMemsetAsync(d_ws, 0, init_bytes, stream);

    hipLaunchKernelGGL(lstm_persist, dim3(NBLK), dim3(NTHR), 0, stream,
                       x, lens, Wi, Wh, bias, out, flags, hbuf);
}